// Round 3
// baseline (7841.449 us; speedup 1.0000x reference)
//
#include <hip/hip_runtime.h>
#include <stdint.h>
#include <stddef.h>

// ---------------- problem constants ----------------
#define kS 512
#define kB 64
#define kD 120
#define kOC 16
#define kKSZ 6
#define kPOOL 114
#define kLIN 1824   // 16*114
#define kH 1024
#define kG 4096
#define kO 48
#define kROWS (kS * kB)  // 32768
#define RNB 64           // recurrence blocks

typedef __attribute__((ext_vector_type(8))) short bf16x8;
typedef __attribute__((ext_vector_type(4))) float f32x4;

__device__ __forceinline__ unsigned short f32_to_bf16(float f) {
  unsigned u = __float_as_uint(f);
  u += 0x7FFFu + ((u >> 16) & 1u);
  return (unsigned short)(u >> 16);
}
__device__ __forceinline__ float bf16_to_f32(unsigned short h) {
  return __uint_as_float(((unsigned)h) << 16);
}
__device__ __forceinline__ float sigmoid_(float x) { return 1.f / (1.f + __expf(-x)); }
__device__ __forceinline__ float tanh_(float x) { return 1.f - 2.f / (__expf(2.f * x) + 1.f); }

__device__ __forceinline__ void load_lds_16(const void* g, void* l) {
  __builtin_amdgcn_global_load_lds((__attribute__((address_space(1))) void*)g,
                                   (__attribute__((address_space(3))) void*)l, 16, 0, 0);
}

// ---------------- K0: weight conversion ----------------
__global__ void convert_weights(const float* __restrict__ wih, const float* __restrict__ whh,
                                const float* __restrict__ h2hw, const float* __restrict__ outw,
                                const float* __restrict__ bih, const float* __restrict__ bhh,
                                unsigned short* __restrict__ wihb, unsigned short* __restrict__ whhb,
                                unsigned short* __restrict__ h2hwb, unsigned short* __restrict__ outwb,
                                float* __restrict__ bsum) {
  const size_t N0 = (size_t)kG * kLIN;
  const size_t N1 = (size_t)kG * kH;
  const size_t N2 = (size_t)kH * kH;
  const size_t N3 = (size_t)kO * kH;
  const size_t N4 = kG;
  const size_t TOT = N0 + N1 + N2 + N3 + N4;
  for (size_t i = (size_t)blockIdx.x * blockDim.x + threadIdx.x; i < TOT;
       i += (size_t)gridDim.x * blockDim.x) {
    if (i < N0) wihb[i] = f32_to_bf16(wih[i]);
    else if (i < N0 + N1) whhb[i - N0] = f32_to_bf16(whh[i - N0]);
    else if (i < N0 + N1 + N2) h2hwb[i - N0 - N1] = f32_to_bf16(h2hw[i - N0 - N1]);
    else if (i < N0 + N1 + N2 + N3) outwb[i - N0 - N1 - N2] = f32_to_bf16(outw[i - N0 - N1 - N2]);
    else { size_t j = i - N0 - N1 - N2 - N3; bsum[j] = bih[j] + bhh[j]; }
  }
}

// ---------------- K1: conv1d + relu + maxpool -> feat bf16 (per-chunk) ----------------
__global__ __launch_bounds__(256) void conv_pool(const float* __restrict__ x,
                                                 const float* __restrict__ cw,
                                                 const float* __restrict__ cb,
                                                 unsigned short* __restrict__ feat,
                                                 long row_base) {
  __shared__ float xs[8][kD];
  __shared__ float ws[kOC][kKSZ];
  __shared__ float bs[kOC];
  const int tid = threadIdx.x;
  const long grow0 = row_base + (long)blockIdx.x * 8;  // global input row
  const long lrow0 = (long)blockIdx.x * 8;             // local feat row
  if (tid < kOC * kKSZ) ws[tid / kKSZ][tid % kKSZ] = cw[tid];
  if (tid < kOC) bs[tid] = cb[tid];
  for (int i = tid; i < 8 * kD; i += 256) xs[i / kD][i % kD] = x[grow0 * kD + i];
  __syncthreads();
  for (int r = 0; r < 8; ++r) {
    for (int idx = tid; idx < kLIN; idx += 256) {
      const int oc = idx / kPOOL, p = idx % kPOOL;
      float c0 = bs[oc], c1 = bs[oc];
#pragma unroll
      for (int k = 0; k < kKSZ; ++k) {
        c0 += xs[r][p + k] * ws[oc][k];
        c1 += xs[r][p + 1 + k] * ws[oc][k];
      }
      float v = fmaxf(fmaxf(c0, c1), 0.f);
      feat[(lrow0 + r) * kLIN + idx] = f32_to_bf16(v);
    }
  }
}

// ---------------- K2/K4: 128x128 bf16 MFMA GEMM, C = act(A @ B^T + bias) ----------------
template <bool RELU>
__global__ __launch_bounds__(256) void gemm_bt_bf16(const unsigned short* __restrict__ A,
                                                    const unsigned short* __restrict__ B,
                                                    const float* __restrict__ bias,
                                                    unsigned short* __restrict__ C,
                                                    int N, int K) {
  __shared__ unsigned short Al[2][128 * 32];
  __shared__ unsigned short Bl[2][128 * 32];
  const int tid = threadIdx.x;
  const int lane = tid & 63;
  const int wid = tid >> 6;
  const int wm = wid >> 1, wn = wid & 1;
  const long bm = (long)blockIdx.x * 128;
  const long bn = (long)blockIdx.y * 128;
  const int NT = K / 32;

  f32x4 acc[4][4] = {};

  auto stage = [&](int buf, int kt) {
    const long k0 = (long)kt * 32;
#pragma unroll
    for (int rnd = 0; rnd < 2; ++rnd) {
      const int chunk = rnd * 256 + tid;  // 0..511
      const int r = chunk >> 2, c = chunk & 3;
      load_lds_16(A + (bm + r) * K + k0 + c * 8, &Al[buf][chunk * 8]);
      load_lds_16(B + (bn + r) * K + k0 + c * 8, &Bl[buf][chunk * 8]);
    }
  };

  stage(0, 0);
  __syncthreads();
  int buf = 0;
  for (int kt = 0; kt < NT; ++kt) {
    if (kt + 1 < NT) stage(buf ^ 1, kt + 1);
    bf16x8 af[4], bfr[4];
#pragma unroll
    for (int i = 0; i < 4; ++i) {
      const int ar = wm * 64 + i * 16 + (lane & 15);
      af[i] = *(const bf16x8*)&Al[buf][ar * 32 + (lane >> 4) * 8];
      const int bc = wn * 64 + i * 16 + (lane & 15);
      bfr[i] = *(const bf16x8*)&Bl[buf][bc * 32 + (lane >> 4) * 8];
    }
#pragma unroll
    for (int i = 0; i < 4; ++i)
#pragma unroll
      for (int j = 0; j < 4; ++j)
        acc[i][j] = __builtin_amdgcn_mfma_f32_16x16x32_bf16(af[i], bfr[j], acc[i][j], 0, 0, 0);
    __syncthreads();
    buf ^= 1;
  }

#pragma unroll
  for (int i = 0; i < 4; ++i) {
#pragma unroll
    for (int j = 0; j < 4; ++j) {
      const long col = bn + wn * 64 + j * 16 + (lane & 15);
      const float bv = bias[col];
#pragma unroll
      for (int e = 0; e < 4; ++e) {
        const long row = bm + wm * 64 + i * 16 + (lane >> 4) * 4 + e;
        float v = acc[i][j][e] + bv;
        if (RELU) v = fmaxf(v, 0.f);
        C[row * N + col] = f32_to_bf16(v);
      }
    }
  }
}

// ---------------- grid barrier (device-scope, persistent kernel) ----------------
__device__ __forceinline__ void grid_barrier(int* cnt, int* gen, int target, int nb) {
  __syncthreads();
  if (threadIdx.x == 0) {
    __threadfence();
    const int prev = __hip_atomic_fetch_add(cnt, 1, __ATOMIC_ACQ_REL, __HIP_MEMORY_SCOPE_AGENT);
    if (prev == target * nb - 1) {
      __hip_atomic_store(gen, target, __ATOMIC_RELEASE, __HIP_MEMORY_SCOPE_AGENT);
    } else {
      while (__hip_atomic_load(gen, __ATOMIC_ACQUIRE, __HIP_MEMORY_SCOPE_AGENT) < target) {
        __builtin_amdgcn_s_sleep(1);
      }
    }
    __threadfence();
  }
  __syncthreads();
}

// ---------------- K3: persistent LSTM recurrence (per-chunk) ----------------
// 64 blocks x 256 thr, 1 block/CU (128KB LDS). Block owns 16 hidden units ->
// 64 gate cols, gate-major: col = g*16 + u so all 4 gates of unit u share lane.
__global__ __launch_bounds__(256) void lstm_rec(const unsigned short* __restrict__ xw,
                                                const unsigned short* __restrict__ whh,
                                                const float* __restrict__ h0,
                                                const float* __restrict__ c0,
                                                float* __restrict__ cst,
                                                unsigned short* __restrict__ hbuf,
                                                unsigned short* __restrict__ hs,
                                                int* __restrict__ bar,
                                                int nsteps, int first, int barbase) {
  __shared__ unsigned short Bl[64 * 1024];  // 128 KB; short idx = kc*512 + col*8 + e
  const int tid = threadIdx.x;
  const int lane = tid & 63;
  const int w = tid >> 6;
  const int urow = lane & 15;
  const int bq = lane >> 4;
  const int u0 = blockIdx.x * 16;

  // stage W_hh slice (64 gate-cols x 1024 K) into LDS, k-tiled layout
  for (int idx = tid; idx < 64 * 128; idx += 256) {
    const int col = idx & 63;
    const int kc = idx >> 6;
    const int gcol = (col >> 4) * kH + u0 + (col & 15);
    *(bf16x8*)&Bl[kc * 512 + col * 8] = *(const bf16x8*)&whh[(long)gcol * kH + kc * 8];
  }
  float creg[4];
  if (first) {
    for (int i = tid; i < 1024; i += 256) {
      const int b = i >> 4, u = i & 15;
      hbuf[b * kH + u0 + u] = f32_to_bf16(h0[b * kH + u0 + u]);
    }
#pragma unroll
    for (int j = 0; j < 4; ++j) {
      const int b = w * 16 + bq * 4 + j;
      creg[j] = c0[b * kH + u0 + urow];
    }
  } else {
#pragma unroll
    for (int j = 0; j < 4; ++j) {
      const int b = w * 16 + bq * 4 + j;
      creg[j] = cst[b * kH + u0 + urow];
    }
  }

  grid_barrier(bar, bar + 1, barbase + 1, RNB);

  for (int t = 0; t < nsteps; ++t) {
    const unsigned short* cur = hbuf + (t & 1) * (kB * kH);
    unsigned short* nxt = hbuf + ((t + 1) & 1) * (kB * kH);

    // precomputed x-part of gates (independent of h)
    float xv[4][4];
#pragma unroll
    for (int j = 0; j < 4; ++j) {
      const int b = w * 16 + bq * 4 + j;
      const unsigned short* xp = xw + (long)(t * kB + b) * kG + u0 + urow;
#pragma unroll
      for (int g = 0; g < 4; ++g) xv[j][g] = bf16_to_f32(xp[g * kH]);
    }

    f32x4 acc[4] = {};
    const unsigned short* arow = cur + (w * 16 + urow) * kH + bq * 8;
#pragma unroll 8
    for (int kt = 0; kt < 32; ++kt) {
      const bf16x8 a = *(const bf16x8*)(arow + kt * 32);
      const int kc = kt * 4 + bq;
#pragma unroll
      for (int g = 0; g < 4; ++g) {
        const bf16x8 bb = *(const bf16x8*)&Bl[kc * 512 + (g * 16 + urow) * 8];
        acc[g] = __builtin_amdgcn_mfma_f32_16x16x32_bf16(a, bb, acc[g], 0, 0, 0);
      }
    }

#pragma unroll
    for (int j = 0; j < 4; ++j) {
      const int b = w * 16 + bq * 4 + j;
      const float gi = sigmoid_(acc[0][j] + xv[j][0]);
      const float gf = sigmoid_(acc[1][j] + xv[j][1]);
      const float gg = tanh_(acc[2][j] + xv[j][2]);
      const float go = sigmoid_(acc[3][j] + xv[j][3]);
      creg[j] = gf * creg[j] + gi * gg;
      const float h = go * tanh_(creg[j]);
      nxt[b * kH + u0 + urow] = f32_to_bf16(h);
      hs[(long)(t * kB + b) * kH + u0 + urow] = f32_to_bf16(fmaxf(h, 0.f));
    }
    grid_barrier(bar, bar + 1, barbase + t + 2, RNB);
  }

#pragma unroll
  for (int j = 0; j < 4; ++j) {
    const int b = w * 16 + bq * 4 + j;
    cst[b * kH + u0 + urow] = creg[j];
  }
}

// ---------------- K5: output head + log_softmax (per-chunk) ----------------
__global__ __launch_bounds__(256) void out_head(const unsigned short* __restrict__ h2,
                                                const unsigned short* __restrict__ ow,
                                                const float* __restrict__ ob,
                                                float* __restrict__ out) {
  __shared__ unsigned short Wl[48 * 1024];  // 96 KB; short idx = kc*384 + col*8 + e
  const int tid = threadIdx.x;
  const int lane = tid & 63;
  const int w = tid >> 6;
  for (int idx = tid; idx < 48 * 128; idx += 256) {
    const int col = idx % 48;
    const int kc = idx / 48;
    *(bf16x8*)&Wl[kc * 384 + col * 8] = *(const bf16x8*)&ow[(long)col * kH + kc * 8];
  }
  __syncthreads();
  const long row0 = (long)blockIdx.x * 64 + w * 16;
  f32x4 acc[3] = {};
  const unsigned short* arow = h2 + (row0 + (lane & 15)) * kH + (lane >> 4) * 8;
#pragma unroll 8
  for (int kt = 0; kt < 32; ++kt) {
    const bf16x8 a = *(const bf16x8*)(arow + kt * 32);
    const int kc = kt * 4 + (lane >> 4);
#pragma unroll
    for (int n = 0; n < 3; ++n) {
      const bf16x8 bb = *(const bf16x8*)&Wl[kc * 384 + (n * 16 + (lane & 15)) * 8];
      acc[n] = __builtin_amdgcn_mfma_f32_16x16x32_bf16(a, bb, acc[n], 0, 0, 0);
    }
  }
  const int colb = lane & 15;
#pragma unroll
  for (int j = 0; j < 4; ++j) {
    float v[3];
#pragma unroll
    for (int n = 0; n < 3; ++n) v[n] = acc[n][j] + ob[n * 16 + colb];
    float m = fmaxf(fmaxf(v[0], v[1]), v[2]);
#pragma unroll
    for (int s = 1; s < 16; s <<= 1) m = fmaxf(m, __shfl_xor(m, s, 64));
    float se = __expf(v[0] - m) + __expf(v[1] - m) + __expf(v[2] - m);
#pragma unroll
    for (int s = 1; s < 16; s <<= 1) se += __shfl_xor(se, s, 64);
    const float lse = m + __logf(se);
    const long row = row0 + (lane >> 4) * 4 + j;
#pragma unroll
    for (int n = 0; n < 3; ++n) out[row * 48 + n * 16 + colb] = v[n] - lse;
  }
}

// ---------------- host ----------------
extern "C" void kernel_launch(void* const* d_in, const int* in_sizes, int n_in,
                              void* d_out, int out_size, void* d_ws, size_t ws_size,
                              hipStream_t stream) {
  const float* input_ = (const float*)d_in[0];
  const float* hidden = (const float*)d_in[1];
  const float* cell = (const float*)d_in[2];
  const float* conv_w = (const float*)d_in[3];
  const float* conv_b = (const float*)d_in[4];
  const float* w_ih = (const float*)d_in[5];
  const float* w_hh = (const float*)d_in[6];
  const float* b_ih = (const float*)d_in[7];
  const float* b_hh = (const float*)d_in[8];
  const float* h2h_w = (const float*)d_in[9];
  const float* h2h_b = (const float*)d_in[10];
  const float* out_w = (const float*)d_in[11];
  const float* out_b = (const float*)d_in[12];
  float* out = (float*)d_out;

  // fixed (chunk-independent) footprint: bf16 weights + bias + state + barrier
  const size_t FIXED = ((size_t)kG * kLIN + (size_t)kG * kH + (size_t)kH * kH +
                        (size_t)kO * kH) * 2 +
                       (size_t)kG * 4 +
                       2 * (size_t)kB * kH * 2 +
                       (size_t)kB * kH * 4 +
                       4096 + 16 * 256;

  // pick largest chunk (timesteps) whose working set fits ws.
  // regionA = feat (rowsC*kLIN bf16), later reused for hs (rowsC*kH, smaller)
  // regionB = xw  (rowsC*kG  bf16), later reused for h2 (rowsC*kH, smaller)
  int CHUNK = 2;
  const int cand[] = {512, 256, 128, 64, 32, 16, 8, 4, 2};
  for (int i = 0; i < 9; ++i) {
    const size_t rowsC = (size_t)cand[i] * kB;
    const size_t need = FIXED + rowsC * (kLIN + kG) * 2;
    if (need <= ws_size) { CHUNK = cand[i]; break; }
  }
  const size_t rowsC = (size_t)CHUNK * kB;

  char* ws = (char*)d_ws;
  size_t off = 0;
  auto alloc = [&](size_t bytes) {
    char* p = ws + off;
    off += (bytes + 255) & ~(size_t)255;
    return p;
  };
  unsigned short* regionA = (unsigned short*)alloc(rowsC * kLIN * 2);
  unsigned short* regionB = (unsigned short*)alloc(rowsC * kG * 2);
  unsigned short* wih_b = (unsigned short*)alloc((size_t)kG * kLIN * 2);
  unsigned short* whh_b = (unsigned short*)alloc((size_t)kG * kH * 2);
  unsigned short* h2hw_b = (unsigned short*)alloc((size_t)kH * kH * 2);
  unsigned short* outw_b = (unsigned short*)alloc((size_t)kO * kH * 2);
  float* bias_sum = (float*)alloc((size_t)kG * 4);
  unsigned short* hbuf = (unsigned short*)alloc(2 * (size_t)kB * kH * 2);
  float* cstate = (float*)alloc((size_t)kB * kH * 4);
  int* bar = (int*)alloc(256);

  unsigned short* feat_c = regionA;
  unsigned short* hs_c = regionA;   // feat dead after gemm<false>
  unsigned short* xw_c = regionB;
  unsigned short* h2_c = regionB;   // xw dead after lstm_rec

  hipMemsetAsync(bar, 0, 256, stream);
  convert_weights<<<2048, 256, 0, stream>>>(w_ih, w_hh, h2h_w, out_w, b_ih, b_hh, wih_b, whh_b,
                                            h2hw_b, outw_b, bias_sum);

  const int nch = kS / CHUNK;
  for (int ci = 0; ci < nch; ++ci) {
    const long t0 = (long)ci * CHUNK;
    conv_pool<<<(int)(rowsC / 8), 256, 0, stream>>>(input_, conv_w, conv_b, feat_c, t0 * kB);
    gemm_bt_bf16<false><<<dim3((int)(rowsC / 128), kG / 128), 256, 0, stream>>>(
        feat_c, wih_b, bias_sum, xw_c, kG, kLIN);
    lstm_rec<<<RNB, 256, 0, stream>>>(xw_c, whh_b, hidden, cell, cstate, hbuf, hs_c, bar, CHUNK,
                                      ci == 0 ? 1 : 0, ci * (CHUNK + 1));
    gemm_bt_bf16<true><<<dim3((int)(rowsC / 128), kH / 128), 256, 0, stream>>>(
        hs_c, h2hw_b, h2h_b, h2_c, kH, kH);
    out_head<<<(int)(rowsC / 64), 256, 0, stream>>>(h2_c, outw_b, out_b, out + t0 * kB * kO);
  }
}